// Round 7
// baseline (573.043 us; speedup 1.0000x reference)
//
#include <hip/hip_runtime.h>
#include <hip/hip_bf16.h>

// ---------------------------------------------------------------------------
// MultiheadAttention: x[2,2048,1024] fp32 -> out[2,2048,1024] fp32. H=16, D=64.
// Round 19: attn key-split x4 for full occupancy. rd6: attn 50us, occupancy
// 33% (grid-limited 16 waves/CU), no pipe >50% -> latency-exposed. Now:
// 512 blocks x 1024 thr = 16 waves (4 key-groups x 4 q-waves, 32 q/wave)
// -> 8192 waves = 32 waves/CU (2 blocks/CU). LDS = exactly 64KB static
// (4 groups x dbuf x 8KB frag-major tiles). Iters 32->16 (half barriers).
// Unshifted base-2 softmax => linear combine O=sum(Of_g), l=sum(li_g):
// 3 sequential f32 handoff rounds through the dead tile space (Of rounds
// grp1/2/3 -> lower 32KB; all li -> upper 32KB round A). T5 setprio around
// MFMA clusters (m191 attn-proven). VGPR must stay <=64 (launch_bounds
// (1024,8)); rd6 measured 60 with identical per-thread state.
//   0) cast2   : x -> xb bf16, wqkv -> wqkvb bf16 into d_out scratch.
//   1) qkv_gemm: 128x128 bf16 MFMA GEMM, global_load_lds(16B) DMA staging,
//                double-buffered; LDS-coalesced Q/K epilogue (rd6). -> Q,K,Vt.
//   2) attn    : transposed flash attention, fragment-major dbuf LDS,
//                key-split x4, 1 barrier/iter.
//   2b) cast wo -> wob bf16 (Q slot, dead after attn).
//   3) out_gemm: 64x128 tile, DMA double-buffered like qkv.
// ws (32 MiB): [Q 8 | K 8 | Vt 8 | AO 8]; wob overlays Q after attn.
// MFMA 16x16x32 bf16 layouts (m89/m91 verified):
//   A-frag: lane holds A[m=lane&15][k=(lane>>4)*8+j]
//   B-frag: lane holds B[k=(lane>>4)*8+j][n=lane&15]
//   C/D   : lane holds D[row=(lane>>4)*4+i][col=lane&15]
// sigma: QK^T A-row r<16 -> key (r>>2)*8+(r&3); row 16+r -> +4. Lane (quad,i)
// holds S[key=quad*8+i] (sA) and S[key=quad*8+4+i] (sB); packed bP[j] =
// P[key=quad*8+j] matches PV's B-frag k-mapping exactly.
// ---------------------------------------------------------------------------

typedef __attribute__((ext_vector_type(8))) short bf16x8;
typedef __attribute__((ext_vector_type(4))) short bf16x4;
typedef __attribute__((ext_vector_type(4))) float f32x4;

#define MFMA16(a, b, c) __builtin_amdgcn_mfma_f32_16x16x32_bf16((a), (b), (c), 0, 0, 0)

#if __has_builtin(__builtin_amdgcn_exp2f)
#define EXP2F(x) __builtin_amdgcn_exp2f(x)
#else
#define EXP2F(x) exp2f(x)
#endif

static __device__ __forceinline__ unsigned short f2bf_bits(float v) {
    __hip_bfloat16 h = __float2bfloat16(v);
    return *reinterpret_cast<unsigned short*>(&h);
}

static __device__ __forceinline__ bf16x8 cvt8(const float* p) {
    const f32x4 a = reinterpret_cast<const f32x4*>(p)[0];
    const f32x4 b = reinterpret_cast<const f32x4*>(p)[1];
    bf16x8 r;
    r[0] = (short)f2bf_bits(a[0]); r[1] = (short)f2bf_bits(a[1]);
    r[2] = (short)f2bf_bits(a[2]); r[3] = (short)f2bf_bits(a[3]);
    r[4] = (short)f2bf_bits(b[0]); r[5] = (short)f2bf_bits(b[1]);
    r[6] = (short)f2bf_bits(b[2]); r[7] = (short)f2bf_bits(b[3]);
    return r;
}

__device__ __forceinline__ bf16x8 ldg8(const __hip_bfloat16* p) {
    return *reinterpret_cast<const bf16x8*>(p);
}

// direct HBM -> LDS DMA, 16 B per lane; lds base must be wave-uniform
__device__ __forceinline__ void load16_lds(const __hip_bfloat16* g, unsigned short* l) {
    __builtin_amdgcn_global_load_lds(
        (const __attribute__((address_space(1))) void*)g,
        (__attribute__((address_space(3))) void*)l, 16, 0, 0);
}

// ---------------------------------------------------------------------------
// Kernel 0: merged cast. blocks [0,512) -> x (4M elems), [512,896) -> wqkv (3M).
// ---------------------------------------------------------------------------
__global__ __launch_bounds__(256)
void cast2_f32_bf16(const float* __restrict__ x, __hip_bfloat16* __restrict__ xb,
                    const float* __restrict__ w, __hip_bfloat16* __restrict__ wb) {
    const int bid = blockIdx.x;
    const float* src = (bid < 512) ? x : w;
    __hip_bfloat16* dst = (bid < 512) ? xb : wb;
    const int rb = (bid < 512) ? bid : (bid - 512);
    const size_t base = (size_t)rb * 8192 + (size_t)threadIdx.x * 32;
#pragma unroll
    for (int i = 0; i < 4; ++i)
        *reinterpret_cast<bf16x8*>(dst + base + i * 8) = cvt8(src + base + i * 8);
}

__global__ __launch_bounds__(256)
void cast_f32_bf16(const float* __restrict__ src, __hip_bfloat16* __restrict__ dst) {
    const size_t base = ((size_t)blockIdx.x * 256 + threadIdx.x) * 32;
#pragma unroll
    for (int i = 0; i < 4; ++i)
        *reinterpret_cast<bf16x8*>(dst + base + i * 8) = cvt8(src + base + i * 8);
}

// ---------------------------------------------------------------------------
// Kernel 1: QKV projection, 128x128 tile, double-buffered DMA staging.
// Q pre-scaled by (1/8)*log2(e). LDS-coalesced Q/K epilogue.
// ---------------------------------------------------------------------------
__global__ __launch_bounds__(256)
void qkv_gemm(const __hip_bfloat16* __restrict__ xb,
              const __hip_bfloat16* __restrict__ wb,
              const float* __restrict__ bqkv,
              __hip_bfloat16* __restrict__ Q,
              __hip_bfloat16* __restrict__ K,
              __hip_bfloat16* __restrict__ Vt) {
    __shared__ unsigned short As[2][128 * 32];   // unpadded (DMA landing rule)
    __shared__ unsigned short Bs[2][128 * 32];

    const int tid  = threadIdx.x;
    const int lane = tid & 63;
    const int wv   = tid >> 6;
    const int quad = lane >> 4;
    const int l16  = lane & 15;
    const int wm   = wv >> 1;
    const int wn   = wv & 1;

    const int bid = blockIdx.x;          // 0..767
    const int xcd = bid & 7;
    const int r   = bid >> 3;            // 0..95
    const int m0  = (r / 3) * 128;
    const int n0  = (xcd * 3 + (r % 3)) * 128;

    // DMA source: lane l -> row base+(l>>2), 16B chunk (l&3)
    const __hip_bfloat16* agl = xb + (size_t)(m0 + wv * 32 + (lane >> 2)) * 1024 + (lane & 3) * 8;
    const __hip_bfloat16* bgl = wb + (size_t)(n0 + wv * 32 + (lane >> 2)) * 1024 + (lane & 3) * 8;

    f32x4 zv = {0.f, 0.f, 0.f, 0.f};
    f32x4 acc[4][4];
#pragma unroll
    for (int ii = 0; ii < 4; ++ii)
#pragma unroll
        for (int jj = 0; jj < 4; ++jj) acc[ii][jj] = zv;

    // prologue: DMA tile 0 into buffer 0
    load16_lds(agl, &As[0][(wv * 32) * 32]);
    load16_lds(agl + 16 * 1024, &As[0][(wv * 32 + 16) * 32]);
    load16_lds(bgl, &Bs[0][(wv * 32) * 32]);
    load16_lds(bgl + 16 * 1024, &Bs[0][(wv * 32 + 16) * 32]);
    __syncthreads();

    for (int k0 = 0; k0 < 1024; k0 += 32) {
        const int p = (k0 >> 5) & 1;
        // prefetch next tile into the other buffer BEFORE compute
        if (k0 + 32 < 1024) {
            const int q = p ^ 1;
            load16_lds(agl + k0 + 32, &As[q][(wv * 32) * 32]);
            load16_lds(agl + 16 * 1024 + k0 + 32, &As[q][(wv * 32 + 16) * 32]);
            load16_lds(bgl + k0 + 32, &Bs[q][(wv * 32) * 32]);
            load16_lds(bgl + 16 * 1024 + k0 + 32, &Bs[q][(wv * 32 + 16) * 32]);
        }
        bf16x8 af[4], bf[4];
#pragma unroll
        for (int ii = 0; ii < 4; ++ii)
            af[ii] = *reinterpret_cast<const bf16x8*>(
                &As[p][(wm * 64 + ii * 16 + l16) * 32 + quad * 8]);
#pragma unroll
        for (int jj = 0; jj < 4; ++jj)
            bf[jj] = *reinterpret_cast<const bf16x8*>(
                &Bs[p][(wn * 64 + jj * 16 + l16) * 32 + quad * 8]);
#pragma unroll
        for (int ii = 0; ii < 4; ++ii)
#pragma unroll
            for (int jj = 0; jj < 4; ++jj)
                acc[ii][jj] = MFMA16(af[ii], bf[jj], acc[ii][jj]);
        __syncthreads();   // drains DMA (mostly overlapped) + guards reuse
    }

    const float QSCALE = 0.18033688011f;   // 0.125 * log2(e)
    const int b  = m0 >> 11;
    const int s0 = m0 & 2047;

    // wave's n-range = [n0 + wn*64, +64): exactly one Q/K/V segment.
    const int nseg  = n0 + wn * 64;
    const int h     = nseg / 192;
    const int r2s   = nseg - h * 192;
    const int ttype = r2s >> 6;            // 0=Q 1=K 2=V (uniform per wave)
    const int bh    = b * 16 + h;

    if (ttype == 2) {
        // V: packed 8B direct stores (as before)
#pragma unroll
        for (int jj = 0; jj < 4; ++jj) {
            const int d = jj * 16 + l16;
            const float bias = bqkv[nseg + d];
#pragma unroll
            for (int ii = 0; ii < 4; ++ii) {
                const int sk = s0 + wm * 64 + ii * 16 + quad * 4;
                bf16x4 pk;
#pragma unroll
                for (int i = 0; i < 4; ++i)
                    pk[i] = (short)f2bf_bits(acc[ii][jj][i] + bias);
                *reinterpret_cast<bf16x4*>(&Vt[((size_t)bh * 64 + d) * 2048 + sk]) = pk;
            }
        }
    } else {
        // Q/K: stage bf16 into LDS tile [128 m][64 n], 16B-chunk XOR swizzle.
        const float scl = (ttype == 0) ? QSCALE : 1.f;
        unsigned short* seg = (wn == 0) ? &As[0][0] : &Bs[0][0];   // 8192 shorts
#pragma unroll
        for (int jj = 0; jj < 4; ++jj) {
            const int nl    = jj * 16 + l16;        // 0..63
            const float bias = bqkv[nseg + nl];
            const int cbase = nl >> 3;
            const int off   = nl & 7;
#pragma unroll
            for (int ii = 0; ii < 4; ++ii) {
#pragma unroll
                for (int i = 0; i < 4; ++i) {
                    const int m = wm * 64 + ii * 16 + quad * 4 + i;   // 0..127
                    const int c = cbase ^ (((m >> 2) & 3) << 1);
                    seg[m * 64 + c * 8 + off] =
                        f2bf_bits((acc[ii][jj][i] + bias) * scl);
                }
            }
        }
    }
    __syncthreads();

    // coalesced copy-out of Q/K segments: 16B/lane, contiguous 16KB region.
#pragma unroll
    for (int sgi = 0; sgi < 2; ++sgi) {
        const int nsg = n0 + sgi * 64;
        const int hh  = nsg / 192;
        const int rr  = nsg - hh * 192;
        const int tt  = rr >> 6;
        if (tt == 2) continue;
        __hip_bfloat16* gbase =
            ((tt == 0) ? Q : K) + ((size_t)(b * 16 + hh) * 2048 + s0) * 64;
        const unsigned short* seg = (sgi == 0) ? &As[0][0] : &Bs[0][0];
#pragma unroll
        for (int p4 = 0; p4 < 4; ++p4) {
            const int L = p4 * 256 + tid;           // 16B-chunk index 0..1023
            const int m = L >> 3;
            const int c = (L & 7) ^ (((m >> 2) & 3) << 1);
            *reinterpret_cast<bf16x8*>(gbase + (size_t)L * 8) =
                *reinterpret_cast<const bf16x8*>(&seg[m * 64 + c * 8]);
        }
    }
}

// ---------------------------------------------------------------------------
// Kernel 2: transposed flash attention, fragment-major LDS, 32 q/wave,
// key-split x4. 512 blocks x 1024 threads:
//   grp = wv>>2 (key quarter, 512 keys), wq = wv&3 (q-subtile, 32 q each).
// Per group: frag-major dbuf tiles SB[grp][buf] (8KB each):
//   frag 0..3 : K A-frags; frag 4..7 : V^T rows. Reads base+lane*16+imm,
//   writes linear 16B/thread -> conflict-free (0 measured rd3..rd6).
// After 16 iters: 3 sequential combine rounds through the dead 64KB tile
// space (Of f32 lower 32KB, li upper 32KB); grp0 normalizes + stores.
// ---------------------------------------------------------------------------
__global__ __launch_bounds__(1024, 8)
void attn_kernel(const __hip_bfloat16* __restrict__ Q,
                 const __hip_bfloat16* __restrict__ K,
                 const __hip_bfloat16* __restrict__ Vt,
                 __hip_bfloat16* __restrict__ AO) {
    __shared__ unsigned short SB[4][2][4096];   // 64KB: [group][buf][8KB]

    const int tid  = threadIdx.x;
    const int lane = tid & 63;
    const int wv   = tid >> 6;           // 0..15
    const int grp  = wv >> 2;            // key quarter
    const int wq   = wv & 3;             // q subtile
    const int quad = lane >> 4;
    const int l16  = lane & 15;

    const int blk = blockIdx.x;          // 0..511
    const int xcd = blk & 7;
    const int sub = blk >> 3;            // 0..63
    const int bh  = xcd * 4 + (sub & 3);
    const int qb  = sub >> 2;            // 0..15
    const int q0  = qb * 128 + wq * 32;
    const int b   = bh >> 4;
    const int h   = bh & 15;
    const int key0 = grp * 512;

    const __hip_bfloat16* Qp = Q  + (size_t)bh * 131072;   // [S,D]
    const __hip_bfloat16* Kp = K  + (size_t)bh * 131072;   // [S,D]
    const __hip_bfloat16* Vp = Vt + (size_t)bh * 131072;   // [D,S]

    bf16x8 bQ[2][2];
#pragma unroll
    for (int t = 0; t < 2; ++t)
#pragma unroll
        for (int dh = 0; dh < 2; ++dh)
            bQ[t][dh] = ldg8(Qp + (size_t)(q0 + t * 16 + l16) * 64 + dh * 32 + quad * 8);

    // --- staging (within group, wave wq stages K frag wq and V frag 4+wq):
    const int keyg = (l16 >> 2) * 8 + (l16 & 3) + ((wq >> 1) << 2);
    const int kd0  = (wq & 1) * 32 + quad * 8;
    const __hip_bfloat16* ksrc = Kp + (size_t)(key0 + keyg) * 64 + kd0;            // step 2048
    const __hip_bfloat16* vsrc = Vp + (size_t)(wq * 16 + l16) * 2048 + key0 + quad * 8;  // step 32

    const int gt = wq * 64 + lane;       // 0..255 within group
    unsigned short* kd[2] = { &SB[grp][0][gt * 8],        &SB[grp][1][gt * 8] };
    unsigned short* vd[2] = { &SB[grp][0][gt * 8 + 2048], &SB[grp][1][gt * 8 + 2048] };

    f32x4 zv = {0.f, 0.f, 0.f, 0.f};
    f32x4 Of[2][4];
#pragma unroll
    for (int t = 0; t < 2; ++t)
#pragma unroll
        for (int jj = 0; jj < 4; ++jj) Of[t][jj] = zv;
    float li[2] = {0.f, 0.f};

    // prologue: tile 0 -> buf 0; prefetch tile 1 into regs
    bf16x8 gk = ldg8(ksrc);
    bf16x8 gv = ldg8(vsrc);
    *reinterpret_cast<bf16x8*>(kd[0]) = gk;
    *reinterpret_cast<bf16x8*>(vd[0]) = gv;
    gk = ldg8(ksrc + 2048);
    gv = ldg8(vsrc + 32);
    __syncthreads();

    for (int kt = 0; kt < 16; ++kt) {
        const int p = kt & 1;
        // publish tile kt+1 (in regs) to the other buffer, then prefetch kt+2
        if (kt < 15) {
            *reinterpret_cast<bf16x8*>(kd[p ^ 1]) = gk;
            *reinterpret_cast<bf16x8*>(vd[p ^ 1]) = gv;
        }
        if (kt < 14) {
            gk = ldg8(ksrc + (size_t)(kt + 2) * 2048);
            gv = ldg8(vsrc + (size_t)(kt + 2) * 32);
        }

        const unsigned short* base = &SB[grp][p][lane * 8];
        const bf16x8 aKA0 = *reinterpret_cast<const bf16x8*>(base + 0 * 512);
        const bf16x8 aKA1 = *reinterpret_cast<const bf16x8*>(base + 1 * 512);
        const bf16x8 aKB0 = *reinterpret_cast<const bf16x8*>(base + 2 * 512);
        const bf16x8 aKB1 = *reinterpret_cast<const bf16x8*>(base + 3 * 512);
        bf16x8 aV[4];
#pragma unroll
        for (int jj = 0; jj < 4; ++jj)
            aV[jj] = *reinterpret_cast<const bf16x8*>(base + (4 + jj) * 512);

        f32x4 sA[2], sB[2];
        __builtin_amdgcn_s_setprio(1);
#pragma unroll
        for (int t = 0; t < 2; ++t) {
            sA[t] = zv; sB[t] = zv;
            sA[t] = MFMA16(aKA0, bQ[t][0], sA[t]);
            sA[t] = MFMA16(aKA1, bQ[t][1], sA[t]);
            sB[t] = MFMA16(aKB0, bQ[t][0], sB[t]);
            sB[t] = MFMA16(aKB1, bQ[t][1], sB[t]);
        }
        __builtin_amdgcn_s_setprio(0);

#pragma unroll
        for (int t = 0; t < 2; ++t) {
            float pA[4], pB[4];
#pragma unroll
            for (int i = 0; i < 4; ++i) {
                pA[i] = EXP2F(sA[t][i]);
                pB[i] = EXP2F(sB[t][i]);
            }
            li[t] += ((pA[0] + pA[1]) + (pA[2] + pA[3]))
                   + ((pB[0] + pB[1]) + (pB[2] + pB[3]));

            bf16x8 bP;
            bP[0] = (short)f2bf_bits(pA[0]); bP[1] = (short)f2bf_bits(pA[1]);
            bP[2] = (short)f2bf_bits(pA[2]); bP[3] = (short)f2bf_bits(pA[3]);
            bP[4] = (short)f2bf_bits(pB[0]); bP[5] = (short)f2bf_bits(pB[1]);
            bP[6] = (short)f2bf_bits(pB[2]); bP[7] = (short)f2bf_bits(pB[3]);

            __builtin_amdgcn_s_setprio(1);
#pragma unroll
            for (int jj = 0; jj < 4; ++jj)
                Of[t][jj] = MFMA16(aV[jj], bP, Of[t][jj]);
            __builtin_amdgcn_s_setprio(0);
        }
        __syncthreads();   // single barrier: publishes buf[p^1], guards buf[p]
    }

#pragma unroll
    for (int t = 0; t < 2; ++t) {
        li[t] += __shfl_xor(li[t], 16);
        li[t] += __shfl_xor(li[t], 32);
    }

    // ---- combine (all tiles dead): Of f32 handoff via lower 32KB,
    //      li via upper 32KB. Sequential rounds grp1 -> grp2 -> grp3.
    f32x4* xf  = reinterpret_cast<f32x4*>(&SB[0][0][0]);   // 2048 slots = 32KB
    float* lix = reinterpret_cast<float*>(&SB[2][0][0]);   // upper 32KB

    // Round A: grp1 Of; all non-zero groups publish li.
    if (grp != 0) {
#pragma unroll
        for (int t = 0; t < 2; ++t)
            lix[((grp - 1) * 4 + wq) * 128 + t * 64 + lane] = li[t];
    }
    if (grp == 1) {
#pragma unroll
        for (int t = 0; t < 2; ++t)
#pragma unroll
            for (int jj = 0; jj < 4; ++jj)
                xf[wq * 512 + (t * 4 + jj) * 64 + lane] = Of[t][jj];
    }
    __syncthreads();
    if (grp == 0) {
#pragma unroll
        for (int t = 0; t < 2; ++t) {
            li[t] += lix[(0 * 4 + wq) * 128 + t * 64 + lane]
                   + lix[(1 * 4 + wq) * 128 + t * 64 + lane]
                   + lix[(2 * 4 + wq) * 128 + t * 64 + lane];
#pragma unroll
            for (int jj = 0; jj < 4; ++jj)
                Of[t][jj] += xf[wq * 512 + (t * 4 + jj) * 64 + lane];
        }
    }
    __syncthreads();
    // Round B: grp2 Of.
    if (grp == 2) {
#pragma unroll
        for (int t = 0; t < 2; ++t)
#pragma unroll
            for (int jj = 0; jj < 4; ++jj)
                xf[wq * 512 + (t * 4 + jj) * 64 + lane] = Of[t][jj];
    }
    __syncthreads();
    if (grp == 0) {
#pragma unroll
        for (int t = 0; t < 2; ++t)
#pragma unroll
            for (int jj = 0; jj < 4; ++jj)
                Of[t][jj] += xf[wq * 512 + (t * 4 + jj) * 64 + lane];
    }
    __syncthreads();
    // Round C: grp3 Of.
    if (grp == 3) {
#pragma unroll
        for (int t = 0; t < 2; ++t)
#pragma unroll
            for (int jj = 0; jj < 4; ++jj)
                xf[wq * 512 + (t * 4 + jj) * 64 + lane] = Of[t][jj];
    }
    __syncthreads();
    if (grp == 0) {
#pragma unroll
        for (int t = 0; t < 2; ++t) {
            const float linv = 1.f / li[t];
            const int s = q0 + t * 16 + l16;
            __hip_bfloat16* aop = AO + (((size_t)b * 2048 + s) * 16 + h) * 64;
#pragma unroll
            for (int jj = 0; jj < 4; ++jj) {
                const f32x4 o2 = xf[wq * 512 + (t * 4 + jj) * 64 + lane];
                bf16x4 pk;
#pragma unroll
                for (int i = 0; i < 4; ++i)
                    pk[i] = (short)f2bf_bits((Of[t][jj][i] + o2[i]) * linv);
                *reinterpret_cast<bf16x4*>(aop + jj * 16 + quad * 4) = pk;
            }
        }
    }
}

// ---------------------------------------------------------------------------
// Kernel 3: output projection, 64(M)x128(N) tile, double-buffered DMA staging.
// 512 blocks = 2/CU. Waves 2x2: wave tile 32(M)x64(N).
// ---------------------------------------------------------------------------
__global__ __launch_bounds__(256)
void out_gemm(const __hip_bfloat16* __restrict__ A,
              const __hip_bfloat16* __restrict__ wob,
              const float* __restrict__ bo,
              float* __restrict__ out) {
    __shared__ unsigned short As[2][64 * 32];    // unpadded
    __shared__ unsigned short Bs[2][128 * 32];

    const int tid  = threadIdx.x;
    const int lane = tid & 63;
    const int wv   = tid >> 6;
    const int quad = lane >> 4;
    const int l16  = lane & 15;
    const int wm   = wv >> 1;
    const int wn   = wv & 1;

    const int bid = blockIdx.x;          // 0..511
    const int m0  = (bid >> 3) * 64;
    const int n0  = (bid & 7) * 128;

    const __hip_bfloat16* agl = A   + (size_t)(m0 + wv * 16 + (lane >> 2)) * 1024 + (lane & 3) * 8;
    const __hip_bfloat16* bgl = wob + (size_t)(n0 + wv * 32 + (lane >> 2)) * 1024 + (lane & 3) * 8;

    f32x4 zv = {0.f, 0.f, 0.f, 0.f};
    f32x4 acc[2][4];
#pragma unroll
    for (int ii = 0; ii < 2; ++ii)
#pragma unroll
        for (int jj = 0; jj < 4; ++jj) acc[ii][jj] = zv;

    load16_lds(agl, &As[0][(wv * 16) * 32]);
    load16_lds(bgl, &Bs[0][(wv * 32) * 32]);
    load16_lds(bgl + 16 * 1024, &Bs[0][(wv * 32 + 16) * 32]);
    __syncthreads();

    for (int k0 = 0; k0 < 1024; k0 += 32) {
        const int p = (k0 >> 5) & 1;
        if (k0 + 32 < 1024) {
            const int q = p ^ 1;
            load16_lds(agl + k0 + 32, &As[q][(wv * 16) * 32]);
            load16_lds(bgl + k0 + 32, &Bs[q][(wv * 32) * 32]);
            load16_lds(bgl + 16 * 1024 + k0 + 32, &Bs[q][(wv * 32 + 16) * 32]);
        }
        bf16x8 af[2], bf[4];
#pragma unroll
        for (int ii = 0; ii < 2; ++ii)
            af[ii] = *reinterpret_cast<const bf16x8*>(
                &As[p][(wm * 32 + ii * 16 + l16) * 32 + quad * 8]);
#pragma unroll
        for (int jj = 0; jj < 4; ++jj)
            bf[jj] = *reinterpret_cast<const bf16x8*>(
                &Bs[p][(wn * 64 + jj * 16 + l16) * 32 + quad * 8]);
#pragma unroll
        for (int ii = 0; ii < 2; ++ii)
#pragma unroll
            for (int jj = 0; jj < 4; ++jj)
                acc[ii][jj] = MFMA16(af[ii], bf[jj], acc[ii][jj]);
        __syncthreads();
    }

#pragma unroll
    for (int jj = 0; jj < 4; ++jj) {
        const int n = n0 + wn * 64 + jj * 16 + l16;
        const float bias = bo[n];
#pragma unroll
        for (int ii = 0; ii < 2; ++ii) {
#pragma unroll
            for (int i = 0; i < 4; ++i) {
                const int m = m0 + wm * 32 + ii * 16 + quad * 4 + i;
                out[(size_t)m * 1024 + n] = acc[ii][jj][i] + bias;
            }
        }
    }
}

// ---------------------------------------------------------------------------
extern "C" void kernel_launch(void* const* d_in, const int* in_sizes, int n_in,
                              void* d_out, int out_size, void* d_ws, size_t ws_size,
                              hipStream_t stream) {
    const float* x    = (const float*)d_in[0];
    const float* wqkv = (const float*)d_in[1];
    const float* bqkv = (const float*)d_in[2];
    const float* wo   = (const float*)d_in[3];
    const float* bo   = (const float*)d_in[4];
    float* out = (float*)d_out;

    __hip_bfloat16* ws = (__hip_bfloat16*)d_ws;
    __hip_bfloat16* Q   = ws;                      // [32,2048,64] (x log2e/8)
    __hip_bfloat16* K   = ws + (size_t)4194304;
    __hip_bfloat16* Vt  = ws + (size_t)8388608;
    __hip_bfloat16* AO  = ws + (size_t)12582912;
    __hip_bfloat16* wob = Q;                       // overlay after attn

    // d_out doubles as pre-pass scratch (dead until out_gemm rewrites it):
    __hip_bfloat16* xb     = (__hip_bfloat16*)d_out;            // 4M elems, 8 MB
    __hip_bfloat16* wqkvb  = xb + (size_t)4194304;              // 3M elems, 6 MB

    // 0) merged casts: x (512 blocks) + wqkv (384 blocks)
    cast2_f32_bf16<<<dim3(896), 256, 0, stream>>>(x, xb, wqkv, wqkvb);
    // 1) QKV projection: M=4096, N=3072, K=1024
    qkv_gemm<<<dim3(768), 256, 0, stream>>>(xb, wqkvb, bqkv, Q, K, Vt);
    // 2) attention: 512 blocks x 16 waves (key-split x4, 32 q/wave)
    attn_kernel<<<dim3(512), 1024, 0, stream>>>(Q, K, Vt, AO);
    // 2b) wo fp32 -> bf16 into dead Q slot (1M elems)
    cast_f32_bf16<<<dim3(128), 256, 0, stream>>>(wo, wob);
    // 3) output projection: M=4096, N=1024, K=1024
    out_gemm<<<dim3(512), 256, 0, stream>>>(AO, wob, bo, out);
}

// Round 8
// 463.385 us; speedup vs baseline: 1.2366x; 1.2366x over previous
//
#include <hip/hip_runtime.h>
#include <hip/hip_bf16.h>

// ---------------------------------------------------------------------------
// MultiheadAttention: x[2,2048,1024] fp32 -> out[2,2048,1024] fp32. H=16, D=64.
// Round 20: rd7 retry with the register allocator UNFORCED. rd7's 428us was
// pure VGPR spill: launch_bounds(1024,8) forced a 64-VGPR budget, allocator
// emitted VGPR=32 + scratch spills (FETCH 819MB, 2.1GB traffic, MfmaUtil 3%).
// Fix: launch_bounds(1024,4) (128-VGPR cap). Identical per-thread state
// compiled to 60 VGPR in rd6 -> expect ~60 here; runtime occupancy is set by
// ACTUAL resources: 60 VGPR (<=64) + 64KB LDS -> 2 blocks x 16 waves =
// 32 waves/CU, rd7's intended occupancy without spills.
// Structure (rd7): 512 blocks x 1024 thr = 16 waves (4 key-groups x 4
// q-waves, 32 q/wave); frag-major dbuf tiles 4x2x8KB = 64KB; 16 iters;
// unshifted base-2 softmax linear combine via 3 LDS handoff rounds.
//   0) cast2   : x -> xb bf16, wqkv -> wqkvb bf16 into d_out scratch.
//   1) qkv_gemm: 128x128 bf16 MFMA GEMM, DMA staging, dbuf;
//                LDS-coalesced Q/K epilogue (rd6). -> Q (x log2e/8), K, Vt.
//   2) attn    : transposed flash attention, key-split x4, 1 barrier/iter.
//   2b) cast wo -> wob bf16 (Q slot, dead after attn).
//   3) out_gemm: 64x128 tile, DMA double-buffered like qkv.
// ws (32 MiB): [Q 8 | K 8 | Vt 8 | AO 8]; wob overlays Q after attn.
// MFMA 16x16x32 bf16 layouts (m89/m91 verified):
//   A-frag: lane holds A[m=lane&15][k=(lane>>4)*8+j]
//   B-frag: lane holds B[k=(lane>>4)*8+j][n=lane&15]
//   C/D   : lane holds D[row=(lane>>4)*4+i][col=lane&15]
// sigma: QK^T A-row r<16 -> key (r>>2)*8+(r&3); row 16+r -> +4. Lane (quad,i)
// holds S[key=quad*8+i] (sA) and S[key=quad*8+4+i] (sB); packed bP[j] =
// P[key=quad*8+j] matches PV's B-frag k-mapping exactly.
// ---------------------------------------------------------------------------

typedef __attribute__((ext_vector_type(8))) short bf16x8;
typedef __attribute__((ext_vector_type(4))) short bf16x4;
typedef __attribute__((ext_vector_type(4))) float f32x4;

#define MFMA16(a, b, c) __builtin_amdgcn_mfma_f32_16x16x32_bf16((a), (b), (c), 0, 0, 0)

#if __has_builtin(__builtin_amdgcn_exp2f)
#define EXP2F(x) __builtin_amdgcn_exp2f(x)
#else
#define EXP2F(x) exp2f(x)
#endif

static __device__ __forceinline__ unsigned short f2bf_bits(float v) {
    __hip_bfloat16 h = __float2bfloat16(v);
    return *reinterpret_cast<unsigned short*>(&h);
}

static __device__ __forceinline__ bf16x8 cvt8(const float* p) {
    const f32x4 a = reinterpret_cast<const f32x4*>(p)[0];
    const f32x4 b = reinterpret_cast<const f32x4*>(p)[1];
    bf16x8 r;
    r[0] = (short)f2bf_bits(a[0]); r[1] = (short)f2bf_bits(a[1]);
    r[2] = (short)f2bf_bits(a[2]); r[3] = (short)f2bf_bits(a[3]);
    r[4] = (short)f2bf_bits(b[0]); r[5] = (short)f2bf_bits(b[1]);
    r[6] = (short)f2bf_bits(b[2]); r[7] = (short)f2bf_bits(b[3]);
    return r;
}

__device__ __forceinline__ bf16x8 ldg8(const __hip_bfloat16* p) {
    return *reinterpret_cast<const bf16x8*>(p);
}

// direct HBM -> LDS DMA, 16 B per lane; lds base must be wave-uniform
__device__ __forceinline__ void load16_lds(const __hip_bfloat16* g, unsigned short* l) {
    __builtin_amdgcn_global_load_lds(
        (const __attribute__((address_space(1))) void*)g,
        (__attribute__((address_space(3))) void*)l, 16, 0, 0);
}

// ---------------------------------------------------------------------------
// Kernel 0: merged cast. blocks [0,512) -> x (4M elems), [512,896) -> wqkv (3M).
// ---------------------------------------------------------------------------
__global__ __launch_bounds__(256)
void cast2_f32_bf16(const float* __restrict__ x, __hip_bfloat16* __restrict__ xb,
                    const float* __restrict__ w, __hip_bfloat16* __restrict__ wb) {
    const int bid = blockIdx.x;
    const float* src = (bid < 512) ? x : w;
    __hip_bfloat16* dst = (bid < 512) ? xb : wb;
    const int rb = (bid < 512) ? bid : (bid - 512);
    const size_t base = (size_t)rb * 8192 + (size_t)threadIdx.x * 32;
#pragma unroll
    for (int i = 0; i < 4; ++i)
        *reinterpret_cast<bf16x8*>(dst + base + i * 8) = cvt8(src + base + i * 8);
}

__global__ __launch_bounds__(256)
void cast_f32_bf16(const float* __restrict__ src, __hip_bfloat16* __restrict__ dst) {
    const size_t base = ((size_t)blockIdx.x * 256 + threadIdx.x) * 32;
#pragma unroll
    for (int i = 0; i < 4; ++i)
        *reinterpret_cast<bf16x8*>(dst + base + i * 8) = cvt8(src + base + i * 8);
}

// ---------------------------------------------------------------------------
// Kernel 1: QKV projection, 128x128 tile, double-buffered DMA staging.
// Q pre-scaled by (1/8)*log2(e). LDS-coalesced Q/K epilogue.
// ---------------------------------------------------------------------------
__global__ __launch_bounds__(256)
void qkv_gemm(const __hip_bfloat16* __restrict__ xb,
              const __hip_bfloat16* __restrict__ wb,
              const float* __restrict__ bqkv,
              __hip_bfloat16* __restrict__ Q,
              __hip_bfloat16* __restrict__ K,
              __hip_bfloat16* __restrict__ Vt) {
    __shared__ unsigned short As[2][128 * 32];   // unpadded (DMA landing rule)
    __shared__ unsigned short Bs[2][128 * 32];

    const int tid  = threadIdx.x;
    const int lane = tid & 63;
    const int wv   = tid >> 6;
    const int quad = lane >> 4;
    const int l16  = lane & 15;
    const int wm   = wv >> 1;
    const int wn   = wv & 1;

    const int bid = blockIdx.x;          // 0..767
    const int xcd = bid & 7;
    const int r   = bid >> 3;            // 0..95
    const int m0  = (r / 3) * 128;
    const int n0  = (xcd * 3 + (r % 3)) * 128;

    // DMA source: lane l -> row base+(l>>2), 16B chunk (l&3)
    const __hip_bfloat16* agl = xb + (size_t)(m0 + wv * 32 + (lane >> 2)) * 1024 + (lane & 3) * 8;
    const __hip_bfloat16* bgl = wb + (size_t)(n0 + wv * 32 + (lane >> 2)) * 1024 + (lane & 3) * 8;

    f32x4 zv = {0.f, 0.f, 0.f, 0.f};
    f32x4 acc[4][4];
#pragma unroll
    for (int ii = 0; ii < 4; ++ii)
#pragma unroll
        for (int jj = 0; jj < 4; ++jj) acc[ii][jj] = zv;

    // prologue: DMA tile 0 into buffer 0
    load16_lds(agl, &As[0][(wv * 32) * 32]);
    load16_lds(agl + 16 * 1024, &As[0][(wv * 32 + 16) * 32]);
    load16_lds(bgl, &Bs[0][(wv * 32) * 32]);
    load16_lds(bgl + 16 * 1024, &Bs[0][(wv * 32 + 16) * 32]);
    __syncthreads();

    for (int k0 = 0; k0 < 1024; k0 += 32) {
        const int p = (k0 >> 5) & 1;
        // prefetch next tile into the other buffer BEFORE compute
        if (k0 + 32 < 1024) {
            const int q = p ^ 1;
            load16_lds(agl + k0 + 32, &As[q][(wv * 32) * 32]);
            load16_lds(agl + 16 * 1024 + k0 + 32, &As[q][(wv * 32 + 16) * 32]);
            load16_lds(bgl + k0 + 32, &Bs[q][(wv * 32) * 32]);
            load16_lds(bgl + 16 * 1024 + k0 + 32, &Bs[q][(wv * 32 + 16) * 32]);
        }
        bf16x8 af[4], bf[4];
#pragma unroll
        for (int ii = 0; ii < 4; ++ii)
            af[ii] = *reinterpret_cast<const bf16x8*>(
                &As[p][(wm * 64 + ii * 16 + l16) * 32 + quad * 8]);
#pragma unroll
        for (int jj = 0; jj < 4; ++jj)
            bf[jj] = *reinterpret_cast<const bf16x8*>(
                &Bs[p][(wn * 64 + jj * 16 + l16) * 32 + quad * 8]);
#pragma unroll
        for (int ii = 0; ii < 4; ++ii)
#pragma unroll
            for (int jj = 0; jj < 4; ++jj)
                acc[ii][jj] = MFMA16(af[ii], bf[jj], acc[ii][jj]);
        __syncthreads();   // drains DMA (mostly overlapped) + guards reuse
    }

    const float QSCALE = 0.18033688011f;   // 0.125 * log2(e)
    const int b  = m0 >> 11;
    const int s0 = m0 & 2047;

    // wave's n-range = [n0 + wn*64, +64): exactly one Q/K/V segment.
    const int nseg  = n0 + wn * 64;
    const int h     = nseg / 192;
    const int r2s   = nseg - h * 192;
    const int ttype = r2s >> 6;            // 0=Q 1=K 2=V (uniform per wave)
    const int bh    = b * 16 + h;

    if (ttype == 2) {
        // V: packed 8B direct stores (as before)
#pragma unroll
        for (int jj = 0; jj < 4; ++jj) {
            const int d = jj * 16 + l16;
            const float bias = bqkv[nseg + d];
#pragma unroll
            for (int ii = 0; ii < 4; ++ii) {
                const int sk = s0 + wm * 64 + ii * 16 + quad * 4;
                bf16x4 pk;
#pragma unroll
                for (int i = 0; i < 4; ++i)
                    pk[i] = (short)f2bf_bits(acc[ii][jj][i] + bias);
                *reinterpret_cast<bf16x4*>(&Vt[((size_t)bh * 64 + d) * 2048 + sk]) = pk;
            }
        }
    } else {
        // Q/K: stage bf16 into LDS tile [128 m][64 n], 16B-chunk XOR swizzle.
        const float scl = (ttype == 0) ? QSCALE : 1.f;
        unsigned short* seg = (wn == 0) ? &As[0][0] : &Bs[0][0];   // 8192 shorts
#pragma unroll
        for (int jj = 0; jj < 4; ++jj) {
            const int nl    = jj * 16 + l16;        // 0..63
            const float bias = bqkv[nseg + nl];
            const int cbase = nl >> 3;
            const int off   = nl & 7;
#pragma unroll
            for (int ii = 0; ii < 4; ++ii) {
#pragma unroll
                for (int i = 0; i < 4; ++i) {
                    const int m = wm * 64 + ii * 16 + quad * 4 + i;   // 0..127
                    const int c = cbase ^ (((m >> 2) & 3) << 1);
                    seg[m * 64 + c * 8 + off] =
                        f2bf_bits((acc[ii][jj][i] + bias) * scl);
                }
            }
        }
    }
    __syncthreads();

    // coalesced copy-out of Q/K segments: 16B/lane, contiguous 16KB region.
#pragma unroll
    for (int sgi = 0; sgi < 2; ++sgi) {
        const int nsg = n0 + sgi * 64;
        const int hh  = nsg / 192;
        const int rr  = nsg - hh * 192;
        const int tt  = rr >> 6;
        if (tt == 2) continue;
        __hip_bfloat16* gbase =
            ((tt == 0) ? Q : K) + ((size_t)(b * 16 + hh) * 2048 + s0) * 64;
        const unsigned short* seg = (sgi == 0) ? &As[0][0] : &Bs[0][0];
#pragma unroll
        for (int p4 = 0; p4 < 4; ++p4) {
            const int L = p4 * 256 + tid;           // 16B-chunk index 0..1023
            const int m = L >> 3;
            const int c = (L & 7) ^ (((m >> 2) & 3) << 1);
            *reinterpret_cast<bf16x8*>(gbase + (size_t)L * 8) =
                *reinterpret_cast<const bf16x8*>(&seg[m * 64 + c * 8]);
        }
    }
}

// ---------------------------------------------------------------------------
// Kernel 2: transposed flash attention, fragment-major LDS, 32 q/wave,
// key-split x4. 512 blocks x 1024 threads:
//   grp = wv>>2 (key quarter, 512 keys), wq = wv&3 (q-subtile, 32 q each).
// launch_bounds(1024,4): 128-VGPR cap, allocator lands ~60 naturally (rd6);
// actual 60 VGPR + 64KB LDS -> 2 blocks/CU = 32 waves/CU at runtime.
// Per group: frag-major dbuf tiles SB[grp][buf] (8KB each):
//   frag 0..3 : K A-frags; frag 4..7 : V^T rows. Reads base+lane*16+imm,
//   writes linear 16B/thread -> conflict-free (0 measured rd3..rd6).
// After 16 iters: 3 sequential combine rounds through the dead 64KB tile
// space (Of f32 lower 32KB, li upper 32KB); grp0 normalizes + stores.
// ---------------------------------------------------------------------------
__global__ __launch_bounds__(1024, 4)
void attn_kernel(const __hip_bfloat16* __restrict__ Q,
                 const __hip_bfloat16* __restrict__ K,
                 const __hip_bfloat16* __restrict__ Vt,
                 __hip_bfloat16* __restrict__ AO) {
    __shared__ unsigned short SB[4][2][4096];   // 64KB: [group][buf][8KB]

    const int tid  = threadIdx.x;
    const int lane = tid & 63;
    const int wv   = tid >> 6;           // 0..15
    const int grp  = wv >> 2;            // key quarter
    const int wq   = wv & 3;             // q subtile
    const int quad = lane >> 4;
    const int l16  = lane & 15;

    const int blk = blockIdx.x;          // 0..511
    const int xcd = blk & 7;
    const int sub = blk >> 3;            // 0..63
    const int bh  = xcd * 4 + (sub & 3);
    const int qb  = sub >> 2;            // 0..15
    const int q0  = qb * 128 + wq * 32;
    const int b   = bh >> 4;
    const int h   = bh & 15;
    const int key0 = grp * 512;

    const __hip_bfloat16* Qp = Q  + (size_t)bh * 131072;   // [S,D]
    const __hip_bfloat16* Kp = K  + (size_t)bh * 131072;   // [S,D]
    const __hip_bfloat16* Vp = Vt + (size_t)bh * 131072;   // [D,S]

    bf16x8 bQ[2][2];
#pragma unroll
    for (int t = 0; t < 2; ++t)
#pragma unroll
        for (int dh = 0; dh < 2; ++dh)
            bQ[t][dh] = ldg8(Qp + (size_t)(q0 + t * 16 + l16) * 64 + dh * 32 + quad * 8);

    // --- staging (within group, wave wq stages K frag wq and V frag 4+wq):
    const int keyg = (l16 >> 2) * 8 + (l16 & 3) + ((wq >> 1) << 2);
    const int kd0  = (wq & 1) * 32 + quad * 8;
    const __hip_bfloat16* ksrc = Kp + (size_t)(key0 + keyg) * 64 + kd0;            // step 2048
    const __hip_bfloat16* vsrc = Vp + (size_t)(wq * 16 + l16) * 2048 + key0 + quad * 8;  // step 32

    const int gt = wq * 64 + lane;       // 0..255 within group
    unsigned short* kd[2] = { &SB[grp][0][gt * 8],        &SB[grp][1][gt * 8] };
    unsigned short* vd[2] = { &SB[grp][0][gt * 8 + 2048], &SB[grp][1][gt * 8 + 2048] };

    f32x4 zv = {0.f, 0.f, 0.f, 0.f};
    f32x4 Of[2][4];
#pragma unroll
    for (int t = 0; t < 2; ++t)
#pragma unroll
        for (int jj = 0; jj < 4; ++jj) Of[t][jj] = zv;
    float li[2] = {0.f, 0.f};

    // prologue: tile 0 -> buf 0; prefetch tile 1 into regs
    bf16x8 gk = ldg8(ksrc);
    bf16x8 gv = ldg8(vsrc);
    *reinterpret_cast<bf16x8*>(kd[0]) = gk;
    *reinterpret_cast<bf16x8*>(vd[0]) = gv;
    gk = ldg8(ksrc + 2048);
    gv = ldg8(vsrc + 32);
    __syncthreads();

    for (int kt = 0; kt < 16; ++kt) {
        const int p = kt & 1;
        // publish tile kt+1 (in regs) to the other buffer, then prefetch kt+2
        if (kt < 15) {
            *reinterpret_cast<bf16x8*>(kd[p ^ 1]) = gk;
            *reinterpret_cast<bf16x8*>(vd[p ^ 1]) = gv;
        }
        if (kt < 14) {
            gk = ldg8(ksrc + (size_t)(kt + 2) * 2048);
            gv = ldg8(vsrc + (size_t)(kt + 2) * 32);
        }

        const unsigned short* base = &SB[grp][p][lane * 8];
        const bf16x8 aKA0 = *reinterpret_cast<const bf16x8*>(base + 0 * 512);
        const bf16x8 aKA1 = *reinterpret_cast<const bf16x8*>(base + 1 * 512);
        const bf16x8 aKB0 = *reinterpret_cast<const bf16x8*>(base + 2 * 512);
        const bf16x8 aKB1 = *reinterpret_cast<const bf16x8*>(base + 3 * 512);
        bf16x8 aV[4];
#pragma unroll
        for (int jj = 0; jj < 4; ++jj)
            aV[jj] = *reinterpret_cast<const bf16x8*>(base + (4 + jj) * 512);

        f32x4 sA[2], sB[2];
        __builtin_amdgcn_s_setprio(1);
#pragma unroll
        for (int t = 0; t < 2; ++t) {
            sA[t] = zv; sB[t] = zv;
            sA[t] = MFMA16(aKA0, bQ[t][0], sA[t]);
            sA[t] = MFMA16(aKA1, bQ[t][1], sA[t]);
            sB[t] = MFMA16(aKB0, bQ[t][0], sB[t]);
            sB[t] = MFMA16(aKB1, bQ[t][1], sB[t]);
        }
        __builtin_amdgcn_s_setprio(0);

#pragma unroll
        for (int t = 0; t < 2; ++t) {
            float pA[4], pB[4];
#pragma unroll
            for (int i = 0; i < 4; ++i) {
                pA[i] = EXP2F(sA[t][i]);
                pB[i] = EXP2F(sB[t][i]);
            }
            li[t] += ((pA[0] + pA[1]) + (pA[2] + pA[3]))
                   + ((pB[0] + pB[1]) + (pB[2] + pB[3]));

            bf16x8 bP;
            bP[0] = (short)f2bf_bits(pA[0]); bP[1] = (short)f2bf_bits(pA[1]);
            bP[2] = (short)f2bf_bits(pA[2]); bP[3] = (short)f2bf_bits(pA[3]);
            bP[4] = (short)f2bf_bits(pB[0]); bP[5] = (short)f2bf_bits(pB[1]);
            bP[6] = (short)f2bf_bits(pB[2]); bP[7] = (short)f2bf_bits(pB[3]);

            __builtin_amdgcn_s_setprio(1);
#pragma unroll
            for (int jj = 0; jj < 4; ++jj)
                Of[t][jj] = MFMA16(aV[jj], bP, Of[t][jj]);
            __builtin_amdgcn_s_setprio(0);
        }
        __syncthreads();   // single barrier: publishes buf[p^1], guards buf[p]
    }

#pragma unroll
    for (int t = 0; t < 2; ++t) {
        li[t] += __shfl_xor(li[t], 16);
        li[t] += __shfl_xor(li[t], 32);
    }

    // ---- combine (all tiles dead): Of f32 handoff via lower 32KB,
    //      li via upper 32KB. Sequential rounds grp1 -> grp2 -> grp3.
    f32x4* xf  = reinterpret_cast<f32x4*>(&SB[0][0][0]);   // 2048 slots = 32KB
    float* lix = reinterpret_cast<float*>(&SB[2][0][0]);   // upper 32KB

    // Round A: grp1 Of; all non-zero groups publish li.
    if (grp != 0) {
#pragma unroll
        for (int t = 0; t < 2; ++t)
            lix[((grp - 1) * 4 + wq) * 128 + t * 64 + lane] = li[t];
    }
    if (grp == 1) {
#pragma unroll
        for (int t = 0; t < 2; ++t)
#pragma unroll
            for (int jj = 0; jj < 4; ++jj)
                xf[wq * 512 + (t * 4 + jj) * 64 + lane] = Of[t][jj];
    }
    __syncthreads();
    if (grp == 0) {
#pragma unroll
        for (int t = 0; t < 2; ++t) {
            li[t] += lix[(0 * 4 + wq) * 128 + t * 64 + lane]
                   + lix[(1 * 4 + wq) * 128 + t * 64 + lane]
                   + lix[(2 * 4 + wq) * 128 + t * 64 + lane];
#pragma unroll
            for (int jj = 0; jj < 4; ++jj)
                Of[t][jj] += xf[wq * 512 + (t * 4 + jj) * 64 + lane];
        }
    }
    __syncthreads();
    // Round B: grp2 Of.
    if (grp == 2) {
#pragma unroll
        for (int t = 0; t < 2; ++t)
#pragma unroll
            for (int jj = 0; jj < 4; ++jj)
                xf[wq * 512 + (t * 4 + jj) * 64 + lane] = Of[t][jj];
    }
    __syncthreads();
    if (grp == 0) {
#pragma unroll
        for (int t = 0; t < 2; ++t)
#pragma unroll
            for (int jj = 0; jj < 4; ++jj)
                Of[t][jj] += xf[wq * 512 + (t * 4 + jj) * 64 + lane];
    }
    __syncthreads();
    // Round C: grp3 Of.
    if (grp == 3) {
#pragma unroll
        for (int t = 0; t < 2; ++t)
#pragma unroll
            for (int jj = 0; jj < 4; ++jj)
                xf[wq * 512 + (t * 4 + jj) * 64 + lane] = Of[t][jj];
    }
    __syncthreads();
    if (grp == 0) {
#pragma unroll
        for (int t = 0; t < 2; ++t) {
            const float linv = 1.f / li[t];
            const int s = q0 + t * 16 + l16;
            __hip_bfloat16* aop = AO + (((size_t)b * 2048 + s) * 16 + h) * 64;
#pragma unroll
            for (int jj = 0; jj < 4; ++jj) {
                const f32x4 o2 = xf[wq * 512 + (t * 4 + jj) * 64 + lane];
                bf16x4 pk;
#pragma unroll
                for (int i = 0; i < 4; ++i)
                    pk[i] = (short)f2bf_bits((Of[t][jj][i] + o2[i]) * linv);
                *reinterpret_cast<bf16x4*>(aop + jj * 16 + quad * 4) = pk;
            }
        }
    }
}

// ---------------------------------------------------------------------------
// Kernel 3: output projection, 64(M)x128(N) tile, double-buffered DMA staging.
// 512 blocks = 2/CU. Waves 2x2: wave tile 32(M)x64(N).
// ---------------------------------------------------------------------------
__global__ __launch_bounds__(256)
void out_gemm(const __hip_bfloat16* __restrict__ A,
              const __hip_bfloat16* __restrict__ wob,
              const float* __restrict__ bo,
              float* __restrict__ out) {
    __shared__ unsigned short As[2][64 * 32];    // unpadded
    __shared__ unsigned short Bs[2][128 * 32];

    const int tid  = threadIdx.x;
    const int lane = tid & 63;
    const int wv   = tid >> 6;
    const int quad = lane >> 4;
    const int l16  = lane & 15;
    const int wm   = wv >> 1;
    const int wn   = wv & 1;

    const int bid = blockIdx.x;          // 0..511
    const int m0  = (bid >> 3) * 64;
    const int n0  = (bid & 7) * 128;

    const __hip_bfloat16* agl = A   + (size_t)(m0 + wv * 16 + (lane >> 2)) * 1024 + (lane & 3) * 8;
    const __hip_bfloat16* bgl = wob + (size_t)(n0 + wv * 32 + (lane >> 2)) * 1024 + (lane & 3) * 8;

    f32x4 zv = {0.f, 0.f, 0.f, 0.f};
    f32x4 acc[2][4];
#pragma unroll
    for (int ii = 0; ii < 2; ++ii)
#pragma unroll
        for (int jj = 0; jj < 4; ++jj) acc[ii][jj] = zv;

    load16_lds(agl, &As[0][(wv * 16) * 32]);
    load16_lds(bgl, &Bs[0][(wv * 32) * 32]);
    load16_lds(bgl + 16 * 1024, &Bs[0][(wv * 32 + 16) * 32]);
    __syncthreads();

    for (int k0 = 0; k0 < 1024; k0 += 32) {
        const int p = (k0 >> 5) & 1;
        if (k0 + 32 < 1024) {
            const int q = p ^ 1;
            load16_lds(agl + k0 + 32, &As[q][(wv * 16) * 32]);
            load16_lds(bgl + k0 + 32, &Bs[q][(wv * 32) * 32]);
            load16_lds(bgl + 16 * 1024 + k0 + 32, &Bs[q][(wv * 32 + 16) * 32]);
        }
        bf16x8 af[2], bf[4];
#pragma unroll
        for (int ii = 0; ii < 2; ++ii)
            af[ii] = *reinterpret_cast<const bf16x8*>(
                &As[p][(wm * 32 + ii * 16 + l16) * 32 + quad * 8]);
#pragma unroll
        for (int jj = 0; jj < 4; ++jj)
            bf[jj] = *reinterpret_cast<const bf16x8*>(
                &Bs[p][(wn * 64 + jj * 16 + l16) * 32 + quad * 8]);
#pragma unroll
        for (int ii = 0; ii < 2; ++ii)
#pragma unroll
            for (int jj = 0; jj < 4; ++jj)
                acc[ii][jj] = MFMA16(af[ii], bf[jj], acc[ii][jj]);
        __syncthreads();
    }

#pragma unroll
    for (int jj = 0; jj < 4; ++jj) {
        const int n = n0 + wn * 64 + jj * 16 + l16;
        const float bias = bo[n];
#pragma unroll
        for (int ii = 0; ii < 2; ++ii) {
#pragma unroll
            for (int i = 0; i < 4; ++i) {
                const int m = m0 + wm * 32 + ii * 16 + quad * 4 + i;
                out[(size_t)m * 1024 + n] = acc[ii][jj][i] + bias;
            }
        }
    }
}

// ---------------------------------------------------------------------------
extern "C" void kernel_launch(void* const* d_in, const int* in_sizes, int n_in,
                              void* d_out, int out_size, void* d_ws, size_t ws_size,
                              hipStream_t stream) {
    const float* x    = (const float*)d_in[0];
    const float* wqkv = (const float*)d_in[1];
    const float* bqkv = (const float*)d_in[2];
    const float* wo   = (const float*)d_in[3];
    const float* bo   = (const float*)d_in[4];
    float* out = (float*)d_out;

    __hip_bfloat16* ws = (__hip_bfloat16*)d_ws;
    __hip_bfloat16* Q   = ws;                      // [32,2048,64] (x log2e/8)
    __hip_bfloat16* K   = ws + (size_t)4194304;
    __hip_bfloat16* Vt  = ws + (size_t)8388608;
    __hip_bfloat16* AO  = ws + (size_t)12582912;
    __hip_bfloat16* wob = Q;                       // overlay after attn

    // d_out doubles as pre-pass scratch (dead until out_gemm rewrites it):
    __hip_bfloat16* xb     = (__hip_bfloat16*)d_out;            // 4M elems, 8 MB
    __hip_bfloat16* wqkvb  = xb + (size_t)4194304;              // 3M elems, 6 MB

    // 0) merged casts: x (512 blocks) + wqkv (384 blocks)
    cast2_f32_bf16<<<dim3(896), 256, 0, stream>>>(x, xb, wqkv, wqkvb);
    // 1) QKV projection: M=4096, N=3072, K=1024
    qkv_gemm<<<dim3(768), 256, 0, stream>>>(xb, wqkvb, bqkv, Q, K, Vt);
    // 2) attention: 512 blocks x 16 waves (key-split x4, 32 q/wave)
    attn_kernel<<<dim3(512), 1024, 0, stream>>>(Q, K, Vt, AO);
    // 2b) wo fp32 -> bf16 into dead Q slot (1M elems)
    cast_f32_bf16<<<dim3(128), 256, 0, stream>>>(wo, wob);
    // 3) output projection: M=4096, N=1024, K=1024
    out_gemm<<<dim3(512), 256, 0, stream>>>(AO, wob, bo, out);
}

// Round 9
// 189.727 us; speedup vs baseline: 3.0204x; 2.4424x over previous
//
#include <hip/hip_runtime.h>
#include <hip/hip_bf16.h>

// ---------------------------------------------------------------------------
// MultiheadAttention: x[2,2048,1024] fp32 -> out[2,2048,1024] fp32. H=16, D=64.
// Round 21: REVERT attn to rd6 structure (proven 50.0us; session best total
// 191.4us) + T5 setprio around MFMA clusters (m191: +4-7% attn).
// rd7/rd8 post-mortem: 1024-thread (16-wave) blocks give the allocator
// HALF the expected VGPR budget (w=8 -> 32, w=4 -> 64) and the ~130-reg
// live set spills to scratch (FETCH 369-819MB, MfmaUtil 3-4%). 16-wave
// blocks are structurally incompatible with this footprint -- abandoned.
//   0) cast2   : x -> xb bf16, wqkv -> wqkvb bf16 into d_out scratch.
//   1) qkv_gemm: 128x128 bf16 MFMA GEMM, global_load_lds(16B) DMA staging,
//                double-buffered; LDS-coalesced Q/K epilogue (rd6). -> Q,K,Vt.
//   2) attn    : transposed flash attention, fragment-major dbuf LDS,
//                in-block key split x2 (512thr, 8 waves), 1 barrier/iter,
//                setprio(1) around MFMA clusters.
//   2b) cast wo -> wob bf16 (Q slot, dead after attn).
//   3) out_gemm: 64x128 tile, DMA double-buffered like qkv.
// ws (32 MiB): [Q 8 | K 8 | Vt 8 | AO 8]; wob overlays Q after attn.
// MFMA 16x16x32 bf16 layouts (m89/m91 verified):
//   A-frag: lane holds A[m=lane&15][k=(lane>>4)*8+j]
//   B-frag: lane holds B[k=(lane>>4)*8+j][n=lane&15]
//   C/D   : lane holds D[row=(lane>>4)*4+i][col=lane&15]
// sigma: QK^T A-row r<16 -> key (r>>2)*8+(r&3); row 16+r -> +4. Lane (quad,i)
// holds S[key=quad*8+i] (sA) and S[key=quad*8+4+i] (sB); packed bP[j] =
// P[key=quad*8+j] matches PV's B-frag k-mapping exactly.
// ---------------------------------------------------------------------------

typedef __attribute__((ext_vector_type(8))) short bf16x8;
typedef __attribute__((ext_vector_type(4))) short bf16x4;
typedef __attribute__((ext_vector_type(4))) float f32x4;

#define MFMA16(a, b, c) __builtin_amdgcn_mfma_f32_16x16x32_bf16((a), (b), (c), 0, 0, 0)

#if __has_builtin(__builtin_amdgcn_exp2f)
#define EXP2F(x) __builtin_amdgcn_exp2f(x)
#else
#define EXP2F(x) exp2f(x)
#endif

static __device__ __forceinline__ unsigned short f2bf_bits(float v) {
    __hip_bfloat16 h = __float2bfloat16(v);
    return *reinterpret_cast<unsigned short*>(&h);
}

static __device__ __forceinline__ bf16x8 cvt8(const float* p) {
    const f32x4 a = reinterpret_cast<const f32x4*>(p)[0];
    const f32x4 b = reinterpret_cast<const f32x4*>(p)[1];
    bf16x8 r;
    r[0] = (short)f2bf_bits(a[0]); r[1] = (short)f2bf_bits(a[1]);
    r[2] = (short)f2bf_bits(a[2]); r[3] = (short)f2bf_bits(a[3]);
    r[4] = (short)f2bf_bits(b[0]); r[5] = (short)f2bf_bits(b[1]);
    r[6] = (short)f2bf_bits(b[2]); r[7] = (short)f2bf_bits(b[3]);
    return r;
}

__device__ __forceinline__ bf16x8 ldg8(const __hip_bfloat16* p) {
    return *reinterpret_cast<const bf16x8*>(p);
}

// direct HBM -> LDS DMA, 16 B per lane; lds base must be wave-uniform
__device__ __forceinline__ void load16_lds(const __hip_bfloat16* g, unsigned short* l) {
    __builtin_amdgcn_global_load_lds(
        (const __attribute__((address_space(1))) void*)g,
        (__attribute__((address_space(3))) void*)l, 16, 0, 0);
}

// ---------------------------------------------------------------------------
// Kernel 0: merged cast. blocks [0,512) -> x (4M elems), [512,896) -> wqkv (3M).
// ---------------------------------------------------------------------------
__global__ __launch_bounds__(256)
void cast2_f32_bf16(const float* __restrict__ x, __hip_bfloat16* __restrict__ xb,
                    const float* __restrict__ w, __hip_bfloat16* __restrict__ wb) {
    const int bid = blockIdx.x;
    const float* src = (bid < 512) ? x : w;
    __hip_bfloat16* dst = (bid < 512) ? xb : wb;
    const int rb = (bid < 512) ? bid : (bid - 512);
    const size_t base = (size_t)rb * 8192 + (size_t)threadIdx.x * 32;
#pragma unroll
    for (int i = 0; i < 4; ++i)
        *reinterpret_cast<bf16x8*>(dst + base + i * 8) = cvt8(src + base + i * 8);
}

__global__ __launch_bounds__(256)
void cast_f32_bf16(const float* __restrict__ src, __hip_bfloat16* __restrict__ dst) {
    const size_t base = ((size_t)blockIdx.x * 256 + threadIdx.x) * 32;
#pragma unroll
    for (int i = 0; i < 4; ++i)
        *reinterpret_cast<bf16x8*>(dst + base + i * 8) = cvt8(src + base + i * 8);
}

// ---------------------------------------------------------------------------
// Kernel 1: QKV projection, 128x128 tile, double-buffered DMA staging.
// Q pre-scaled by (1/8)*log2(e). LDS-coalesced Q/K epilogue.
// ---------------------------------------------------------------------------
__global__ __launch_bounds__(256)
void qkv_gemm(const __hip_bfloat16* __restrict__ xb,
              const __hip_bfloat16* __restrict__ wb,
              const float* __restrict__ bqkv,
              __hip_bfloat16* __restrict__ Q,
              __hip_bfloat16* __restrict__ K,
              __hip_bfloat16* __restrict__ Vt) {
    __shared__ unsigned short As[2][128 * 32];   // unpadded (DMA landing rule)
    __shared__ unsigned short Bs[2][128 * 32];

    const int tid  = threadIdx.x;
    const int lane = tid & 63;
    const int wv   = tid >> 6;
    const int quad = lane >> 4;
    const int l16  = lane & 15;
    const int wm   = wv >> 1;
    const int wn   = wv & 1;

    const int bid = blockIdx.x;          // 0..767
    const int xcd = bid & 7;
    const int r   = bid >> 3;            // 0..95
    const int m0  = (r / 3) * 128;
    const int n0  = (xcd * 3 + (r % 3)) * 128;

    // DMA source: lane l -> row base+(l>>2), 16B chunk (l&3)
    const __hip_bfloat16* agl = xb + (size_t)(m0 + wv * 32 + (lane >> 2)) * 1024 + (lane & 3) * 8;
    const __hip_bfloat16* bgl = wb + (size_t)(n0 + wv * 32 + (lane >> 2)) * 1024 + (lane & 3) * 8;

    f32x4 zv = {0.f, 0.f, 0.f, 0.f};
    f32x4 acc[4][4];
#pragma unroll
    for (int ii = 0; ii < 4; ++ii)
#pragma unroll
        for (int jj = 0; jj < 4; ++jj) acc[ii][jj] = zv;

    // prologue: DMA tile 0 into buffer 0
    load16_lds(agl, &As[0][(wv * 32) * 32]);
    load16_lds(agl + 16 * 1024, &As[0][(wv * 32 + 16) * 32]);
    load16_lds(bgl, &Bs[0][(wv * 32) * 32]);
    load16_lds(bgl + 16 * 1024, &Bs[0][(wv * 32 + 16) * 32]);
    __syncthreads();

    for (int k0 = 0; k0 < 1024; k0 += 32) {
        const int p = (k0 >> 5) & 1;
        // prefetch next tile into the other buffer BEFORE compute
        if (k0 + 32 < 1024) {
            const int q = p ^ 1;
            load16_lds(agl + k0 + 32, &As[q][(wv * 32) * 32]);
            load16_lds(agl + 16 * 1024 + k0 + 32, &As[q][(wv * 32 + 16) * 32]);
            load16_lds(bgl + k0 + 32, &Bs[q][(wv * 32) * 32]);
            load16_lds(bgl + 16 * 1024 + k0 + 32, &Bs[q][(wv * 32 + 16) * 32]);
        }
        bf16x8 af[4], bf[4];
#pragma unroll
        for (int ii = 0; ii < 4; ++ii)
            af[ii] = *reinterpret_cast<const bf16x8*>(
                &As[p][(wm * 64 + ii * 16 + l16) * 32 + quad * 8]);
#pragma unroll
        for (int jj = 0; jj < 4; ++jj)
            bf[jj] = *reinterpret_cast<const bf16x8*>(
                &Bs[p][(wn * 64 + jj * 16 + l16) * 32 + quad * 8]);
#pragma unroll
        for (int ii = 0; ii < 4; ++ii)
#pragma unroll
            for (int jj = 0; jj < 4; ++jj)
                acc[ii][jj] = MFMA16(af[ii], bf[jj], acc[ii][jj]);
        __syncthreads();   // drains DMA (mostly overlapped) + guards reuse
    }

    const float QSCALE = 0.18033688011f;   // 0.125 * log2(e)
    const int b  = m0 >> 11;
    const int s0 = m0 & 2047;

    // wave's n-range = [n0 + wn*64, +64): exactly one Q/K/V segment.
    const int nseg  = n0 + wn * 64;
    const int h     = nseg / 192;
    const int r2s   = nseg - h * 192;
    const int ttype = r2s >> 6;            // 0=Q 1=K 2=V (uniform per wave)
    const int bh    = b * 16 + h;

    if (ttype == 2) {
        // V: packed 8B direct stores (as before)
#pragma unroll
        for (int jj = 0; jj < 4; ++jj) {
            const int d = jj * 16 + l16;
            const float bias = bqkv[nseg + d];
#pragma unroll
            for (int ii = 0; ii < 4; ++ii) {
                const int sk = s0 + wm * 64 + ii * 16 + quad * 4;
                bf16x4 pk;
#pragma unroll
                for (int i = 0; i < 4; ++i)
                    pk[i] = (short)f2bf_bits(acc[ii][jj][i] + bias);
                *reinterpret_cast<bf16x4*>(&Vt[((size_t)bh * 64 + d) * 2048 + sk]) = pk;
            }
        }
    } else {
        // Q/K: stage bf16 into LDS tile [128 m][64 n], 16B-chunk XOR swizzle.
        const float scl = (ttype == 0) ? QSCALE : 1.f;
        unsigned short* seg = (wn == 0) ? &As[0][0] : &Bs[0][0];   // 8192 shorts
#pragma unroll
        for (int jj = 0; jj < 4; ++jj) {
            const int nl    = jj * 16 + l16;        // 0..63
            const float bias = bqkv[nseg + nl];
            const int cbase = nl >> 3;
            const int off   = nl & 7;
#pragma unroll
            for (int ii = 0; ii < 4; ++ii) {
#pragma unroll
                for (int i = 0; i < 4; ++i) {
                    const int m = wm * 64 + ii * 16 + quad * 4 + i;   // 0..127
                    const int c = cbase ^ (((m >> 2) & 3) << 1);
                    seg[m * 64 + c * 8 + off] =
                        f2bf_bits((acc[ii][jj][i] + bias) * scl);
                }
            }
        }
    }
    __syncthreads();

    // coalesced copy-out of Q/K segments: 16B/lane, contiguous 16KB region.
#pragma unroll
    for (int sgi = 0; sgi < 2; ++sgi) {
        const int nsg = n0 + sgi * 64;
        const int hh  = nsg / 192;
        const int rr  = nsg - hh * 192;
        const int tt  = rr >> 6;
        if (tt == 2) continue;
        __hip_bfloat16* gbase =
            ((tt == 0) ? Q : K) + ((size_t)(b * 16 + hh) * 2048 + s0) * 64;
        const unsigned short* seg = (sgi == 0) ? &As[0][0] : &Bs[0][0];
#pragma unroll
        for (int p4 = 0; p4 < 4; ++p4) {
            const int L = p4 * 256 + tid;           // 16B-chunk index 0..1023
            const int m = L >> 3;
            const int c = (L & 7) ^ (((m >> 2) & 3) << 1);
            *reinterpret_cast<bf16x8*>(gbase + (size_t)L * 8) =
                *reinterpret_cast<const bf16x8*>(&seg[m * 64 + c * 8]);
        }
    }
}

// ---------------------------------------------------------------------------
// Kernel 2: transposed flash attention, fragment-major LDS, 32 q/wave,
// in-block key split x2. 512 blocks x 512 threads:
//   grp = wv>>2 (key half), wq = wv&3 (q-subtile, 32 q each).
// Per group: frag-major dbuf tiles SB[grp][buf] (8KB each):
//   frag 0..3 : K A-frags; frag 4..7 : V^T rows. Reads base+lane*16+imm,
//   writes linear 16B/thread -> conflict-free (0 measured rd3..rd6).
// After 32 iters: group 1 writes Of (f32x4, lane-major) + li into the dead
// staging LDS; group 0 adds, normalizes by 1/(l0+l1), stores AO.
// T5: setprio(1) around MFMA clusters (m191 attn-proven).
// ---------------------------------------------------------------------------
__global__ __launch_bounds__(512, 4)
void attn_kernel(const __hip_bfloat16* __restrict__ Q,
                 const __hip_bfloat16* __restrict__ K,
                 const __hip_bfloat16* __restrict__ Vt,
                 __hip_bfloat16* __restrict__ AO) {
    __shared__ unsigned short SB[2][2][4096];   // [group][buf][8KB frag-major]
    __shared__ float LiX[4][2][64];             // group-1 li handoff

    const int tid  = threadIdx.x;
    const int lane = tid & 63;
    const int wv   = tid >> 6;           // 0..7
    const int grp  = wv >> 2;            // key half
    const int wq   = wv & 3;             // q subtile
    const int quad = lane >> 4;
    const int l16  = lane & 15;

    const int blk = blockIdx.x;          // 0..511
    const int xcd = blk & 7;
    const int sub = blk >> 3;            // 0..63
    const int bh  = xcd * 4 + (sub & 3);
    const int qb  = sub >> 2;            // 0..15
    const int q0  = qb * 128 + wq * 32;
    const int b   = bh >> 4;
    const int h   = bh & 15;
    const int key0 = grp * 1024;

    const __hip_bfloat16* Qp = Q  + (size_t)bh * 131072;   // [S,D]
    const __hip_bfloat16* Kp = K  + (size_t)bh * 131072;   // [S,D]
    const __hip_bfloat16* Vp = Vt + (size_t)bh * 131072;   // [D,S]

    bf16x8 bQ[2][2];
#pragma unroll
    for (int t = 0; t < 2; ++t)
#pragma unroll
        for (int dh = 0; dh < 2; ++dh)
            bQ[t][dh] = ldg8(Qp + (size_t)(q0 + t * 16 + l16) * 64 + dh * 32 + quad * 8);

    // --- staging (within group, wave wq stages K frag wq and V frag 4+wq):
    const int keyg = (l16 >> 2) * 8 + (l16 & 3) + ((wq >> 1) << 2);
    const int kd0  = (wq & 1) * 32 + quad * 8;
    const __hip_bfloat16* ksrc = Kp + (size_t)(key0 + keyg) * 64 + kd0;            // step 2048
    const __hip_bfloat16* vsrc = Vp + (size_t)(wq * 16 + l16) * 2048 + key0 + quad * 8;  // step 32

    const int gt = wq * 64 + lane;       // 0..255 within group
    unsigned short* kd[2] = { &SB[grp][0][gt * 8],        &SB[grp][1][gt * 8] };
    unsigned short* vd[2] = { &SB[grp][0][gt * 8 + 2048], &SB[grp][1][gt * 8 + 2048] };

    f32x4 zv = {0.f, 0.f, 0.f, 0.f};
    f32x4 Of[2][4];
#pragma unroll
    for (int t = 0; t < 2; ++t)
#pragma unroll
        for (int jj = 0; jj < 4; ++jj) Of[t][jj] = zv;
    float li[2] = {0.f, 0.f};

    // prologue: tile 0 -> buf 0; prefetch tile 1 into regs
    bf16x8 gk = ldg8(ksrc);
    bf16x8 gv = ldg8(vsrc);
    *reinterpret_cast<bf16x8*>(kd[0]) = gk;
    *reinterpret_cast<bf16x8*>(vd[0]) = gv;
    gk = ldg8(ksrc + 2048);
    gv = ldg8(vsrc + 32);
    __syncthreads();

    for (int kt = 0; kt < 32; ++kt) {
        const int p = kt & 1;
        // publish tile kt+1 (in regs) to the other buffer, then prefetch kt+2
        if (kt < 31) {
            *reinterpret_cast<bf16x8*>(kd[p ^ 1]) = gk;
            *reinterpret_cast<bf16x8*>(vd[p ^ 1]) = gv;
        }
        if (kt < 30) {
            gk = ldg8(ksrc + (size_t)(kt + 2) * 2048);
            gv = ldg8(vsrc + (size_t)(kt + 2) * 32);
        }

        const unsigned short* base = &SB[grp][p][lane * 8];
        const bf16x8 aKA0 = *reinterpret_cast<const bf16x8*>(base + 0 * 512);
        const bf16x8 aKA1 = *reinterpret_cast<const bf16x8*>(base + 1 * 512);
        const bf16x8 aKB0 = *reinterpret_cast<const bf16x8*>(base + 2 * 512);
        const bf16x8 aKB1 = *reinterpret_cast<const bf16x8*>(base + 3 * 512);
        bf16x8 aV[4];
#pragma unroll
        for (int jj = 0; jj < 4; ++jj)
            aV[jj] = *reinterpret_cast<const bf16x8*>(base + (4 + jj) * 512);

        f32x4 sA[2], sB[2];
        __builtin_amdgcn_s_setprio(1);
#pragma unroll
        for (int t = 0; t < 2; ++t) {
            sA[t] = zv; sB[t] = zv;
            sA[t] = MFMA16(aKA0, bQ[t][0], sA[t]);
            sA[t] = MFMA16(aKA1, bQ[t][1], sA[t]);
            sB[t] = MFMA16(aKB0, bQ[t][0], sB[t]);
            sB[t] = MFMA16(aKB1, bQ[t][1], sB[t]);
        }
        __builtin_amdgcn_s_setprio(0);

#pragma unroll
        for (int t = 0; t < 2; ++t) {
            float pA[4], pB[4];
#pragma unroll
            for (int i = 0; i < 4; ++i) {
                pA[i] = EXP2F(sA[t][i]);
                pB[i] = EXP2F(sB[t][i]);
            }
            li[t] += ((pA[0] + pA[1]) + (pA[2] + pA[3]))
                   + ((pB[0] + pB[1]) + (pB[2] + pB[3]));

            bf16x8 bP;
            bP[0] = (short)f2bf_bits(pA[0]); bP[1] = (short)f2bf_bits(pA[1]);
            bP[2] = (short)f2bf_bits(pA[2]); bP[3] = (short)f2bf_bits(pA[3]);
            bP[4] = (short)f2bf_bits(pB[0]); bP[5] = (short)f2bf_bits(pB[1]);
            bP[6] = (short)f2bf_bits(pB[2]); bP[7] = (short)f2bf_bits(pB[3]);

            __builtin_amdgcn_s_setprio(1);
#pragma unroll
            for (int jj = 0; jj < 4; ++jj)
                Of[t][jj] = MFMA16(aV[jj], bP, Of[t][jj]);
            __builtin_amdgcn_s_setprio(0);
        }
        __syncthreads();   // single barrier: publishes buf[p^1], guards buf[p]
    }

#pragma unroll
    for (int t = 0; t < 2; ++t) {
        li[t] += __shfl_xor(li[t], 16);
        li[t] += __shfl_xor(li[t], 32);
    }

    // ---- combine: group 1 -> LDS (staging buffers are dead now) ----
    // layout: f32x4 slot = wq*512 + (t*4+jj)*64 + lane  (lane-major, 16B
    // stride -> conflict-free). 4 waves * 8KB = 32KB = all of SB.
    f32x4* xf = reinterpret_cast<f32x4*>(&SB[0][0][0]);
    if (grp == 1) {
#pragma unroll
        for (int t = 0; t < 2; ++t) {
            LiX[wq][t][lane] = li[t];
#pragma unroll
            for (int jj = 0; jj < 4; ++jj)
                xf[wq * 512 + (t * 4 + jj) * 64 + lane] = Of[t][jj];
        }
    }
    __syncthreads();
    if (grp == 0) {
#pragma unroll
        for (int t = 0; t < 2; ++t) {
            const float linv = 1.f / (li[t] + LiX[wq][t][lane]);
            const int s = q0 + t * 16 + l16;
            __hip_bfloat16* aop = AO + (((size_t)b * 2048 + s) * 16 + h) * 64;
#pragma unroll
            for (int jj = 0; jj < 4; ++jj) {
                const f32x4 o2 = xf[wq * 512 + (t * 4 + jj) * 64 + lane];
                bf16x4 pk;
#pragma unroll
                for (int i = 0; i < 4; ++i)
                    pk[i] = (short)f2bf_bits((Of[t][jj][i] + o2[i]) * linv);
                *reinterpret_cast<bf16x4*>(aop + jj * 16 + quad * 4) = pk;
            }
        }
    }
}

// ---------------------------------------------------------------------------
// Kernel 3: output projection, 64(M)x128(N) tile, double-buffered DMA staging.
// 512 blocks = 2/CU. Waves 2x2: wave tile 32(M)x64(N).
// ---------------------------------------------------------------------------
__global__ __launch_bounds__(256)
void out_gemm(const __hip_bfloat16* __restrict__ A,
              const __hip_bfloat16* __restrict__ wob,
              const float* __restrict__ bo,
              float* __restrict__ out) {
    __shared__ unsigned short As[2][64 * 32];    // unpadded
    __shared__ unsigned short Bs[2][128 * 32];

    const int tid  = threadIdx.x;
    const int lane = tid & 63;
    const int wv   = tid >> 6;
    const int quad = lane >> 4;
    const int l16  = lane & 15;
    const int wm   = wv >> 1;
    const int wn   = wv & 1;

    const int bid = blockIdx.x;          // 0..511
    const int m0  = (bid >> 3) * 64;
    const int n0  = (bid & 7) * 128;

    const __hip_bfloat16* agl = A   + (size_t)(m0 + wv * 16 + (lane >> 2)) * 1024 + (lane & 3) * 8;
    const __hip_bfloat16* bgl = wob + (size_t)(n0 + wv * 32 + (lane >> 2)) * 1024 + (lane & 3) * 8;

    f32x4 zv = {0.f, 0.f, 0.f, 0.f};
    f32x4 acc[2][4];
#pragma unroll
    for (int ii = 0; ii < 2; ++ii)
#pragma unroll
        for (int jj = 0; jj < 4; ++jj) acc[ii][jj] = zv;

    load16_lds(agl, &As[0][(wv * 16) * 32]);
    load16_lds(bgl, &Bs[0][(wv * 32) * 32]);
    load16_lds(bgl + 16 * 1024, &Bs[0][(wv * 32 + 16) * 32]);
    __syncthreads();

    for (int k0 = 0; k0 < 1024; k0 += 32) {
        const int p = (k0 >> 5) & 1;
        if (k0 + 32 < 1024) {
            const int q = p ^ 1;
            load16_lds(agl + k0 + 32, &As[q][(wv * 16) * 32]);
            load16_lds(bgl + k0 + 32, &Bs[q][(wv * 32) * 32]);
            load16_lds(bgl + 16 * 1024 + k0 + 32, &Bs[q][(wv * 32 + 16) * 32]);
        }
        bf16x8 af[2], bf[4];
#pragma unroll
        for (int ii = 0; ii < 2; ++ii)
            af[ii] = *reinterpret_cast<const bf16x8*>(
                &As[p][(wm * 32 + ii * 16 + l16) * 32 + quad * 8]);
#pragma unroll
        for (int jj = 0; jj < 4; ++jj)
            bf[jj] = *reinterpret_cast<const bf16x8*>(
                &Bs[p][(wn * 64 + jj * 16 + l16) * 32 + quad * 8]);
#pragma unroll
        for (int ii = 0; ii < 2; ++ii)
#pragma unroll
            for (int jj = 0; jj < 4; ++jj)
                acc[ii][jj] = MFMA16(af[ii], bf[jj], acc[ii][jj]);
        __syncthreads();
    }

#pragma unroll
    for (int jj = 0; jj < 4; ++jj) {
        const int n = n0 + wn * 64 + jj * 16 + l16;
        const float bias = bo[n];
#pragma unroll
        for (int ii = 0; ii < 2; ++ii) {
#pragma unroll
            for (int i = 0; i < 4; ++i) {
                const int m = m0 + wm * 32 + ii * 16 + quad * 4 + i;
                out[(size_t)m * 1024 + n] = acc[ii][jj][i] + bias;
            }
        }
    }
}

// ---------------------------------------------------------------------------
extern "C" void kernel_launch(void* const* d_in, const int* in_sizes, int n_in,
                              void* d_out, int out_size, void* d_ws, size_t ws_size,
                              hipStream_t stream) {
    const float* x    = (const float*)d_in[0];
    const float* wqkv = (const float*)d_in[1];
    const float* bqkv = (const float*)d_in[2];
    const float* wo   = (const float*)d_in[3];
    const float* bo   = (const float*)d_in[4];
    float* out = (float*)d_out;

    __hip_bfloat16* ws = (__hip_bfloat16*)d_ws;
    __hip_bfloat16* Q   = ws;                      // [32,2048,64] (x log2e/8)
    __hip_bfloat16* K   = ws + (size_t)4194304;
    __hip_bfloat16* Vt  = ws + (size_t)8388608;
    __hip_bfloat16* AO  = ws + (size_t)12582912;
    __hip_bfloat16* wob = Q;                       // overlay after attn

    // d_out doubles as pre-pass scratch (dead until out_gemm rewrites it):
    __hip_bfloat16* xb     = (__hip_bfloat16*)d_out;            // 4M elems, 8 MB
    __hip_bfloat16* wqkvb  = xb + (size_t)4194304;              // 3M elems, 6 MB

    // 0) merged casts: x (512 blocks) + wqkv (384 blocks)
    cast2_f32_bf16<<<dim3(896), 256, 0, stream>>>(x, xb, wqkv, wqkvb);
    // 1) QKV projection: M=4096, N=3072, K=1024
    qkv_gemm<<<dim3(768), 256, 0, stream>>>(xb, wqkvb, bqkv, Q, K, Vt);
    // 2) attention: 512 blocks x 8 waves (key-split x2, 32 q/wave)
    attn_kernel<<<dim3(512), 512, 0, stream>>>(Q, K, Vt, AO);
    // 2b) wo fp32 -> bf16 into dead Q slot (1M elems)
    cast_f32_bf16<<<dim3(128), 256, 0, stream>>>(wo, wob);
    // 3) output projection: M=4096, N=1024, K=1024
    out_gemm<<<dim3(512), 256, 0, stream>>>(AO, wob, bo, out);
}